// Round 13
// baseline (211.331 us; speedup 1.0000x reference)
//
#include <hip/hip_runtime.h>

#define DMODEL 1024
#define NEXP   32
#define FDIM   512
#define TOPK   4

#define MT    128   // token tile
#define NT    128   // f / v tile
#define BK    32
#define PITCH 40    // ushorts per LDS row (80 B, 5 quads, odd -> conflict-free)
#define RTB   8     // tokens per routing block
#define NBORD 64    // blocks for hist/scatter phases

using short8 = __attribute__((ext_vector_type(8))) short;
using f32x4  = __attribute__((ext_vector_type(4))) float;

__device__ __forceinline__ unsigned short f2b(float f) {
    unsigned int u = __float_as_uint(f);
    unsigned int r = (u + 0x7FFFu + ((u >> 16) & 1u)) >> 16;   // RNE bf16
    return (unsigned short)r;
}

// ------- phase A: gates + top-4 -> sel arrays (NO atomics) + x->bf16 -------
__global__ __launch_bounds__(256) void route_a(
    const float* __restrict__ x, const float* __restrict__ esel,
    unsigned short* __restrict__ xb,
    unsigned int* __restrict__ sel_e, float* __restrict__ sel_g, int ntok)
{
    int tile0 = blockIdx.x * RTB;
    int tid = threadIdx.x;

    __shared__ float xs[RTB][DMODEL];   // 32 KB
    __shared__ float gs[RTB][NEXP];     // 1 KB

    {
        const float4* src = (const float4*)(x + (size_t)tile0 * DMODEL);
        float4* dst = (float4*)&xs[0][0];
        int navail = min(RTB, ntok - tile0) * (DMODEL / 4);
        for (int i = tid; i < RTB * (DMODEL / 4); i += 256)
            dst[i] = src[i < navail ? i : 0];
    }
    __syncthreads();

    // dot phase: thread (e = tid>>3, sub = tid&7); esel read coalesced, j-outer
    int e = tid >> 3, sub = tid & 7;
    float4 acc0 = {0,0,0,0}, acc1 = {0,0,0,0}, acc2 = {0,0,0,0}, acc3 = {0,0,0,0};
    float4 acc4 = {0,0,0,0}, acc5 = {0,0,0,0}, acc6 = {0,0,0,0}, acc7 = {0,0,0,0};
    const float* er = esel + (size_t)e * DMODEL + sub * 4;
    #pragma unroll 4
    for (int j = 0; j < DMODEL / 32; j++) {
        float4 ev = *(const float4*)(er + j * 32);
        int kk = sub * 4 + j * 32;
        float4 x0 = *(const float4*)(&xs[0][kk]);
        float4 x1 = *(const float4*)(&xs[1][kk]);
        float4 x2 = *(const float4*)(&xs[2][kk]);
        float4 x3 = *(const float4*)(&xs[3][kk]);
        float4 x4 = *(const float4*)(&xs[4][kk]);
        float4 x5 = *(const float4*)(&xs[5][kk]);
        float4 x6 = *(const float4*)(&xs[6][kk]);
        float4 x7 = *(const float4*)(&xs[7][kk]);
        acc0.x += ev.x*x0.x; acc0.y += ev.y*x0.y; acc0.z += ev.z*x0.z; acc0.w += ev.w*x0.w;
        acc1.x += ev.x*x1.x; acc1.y += ev.y*x1.y; acc1.z += ev.z*x1.z; acc1.w += ev.w*x1.w;
        acc2.x += ev.x*x2.x; acc2.y += ev.y*x2.y; acc2.z += ev.z*x2.z; acc2.w += ev.w*x2.w;
        acc3.x += ev.x*x3.x; acc3.y += ev.y*x3.y; acc3.z += ev.z*x3.z; acc3.w += ev.w*x3.w;
        acc4.x += ev.x*x4.x; acc4.y += ev.y*x4.y; acc4.z += ev.z*x4.z; acc4.w += ev.w*x4.w;
        acc5.x += ev.x*x5.x; acc5.y += ev.y*x5.y; acc5.z += ev.z*x5.z; acc5.w += ev.w*x5.w;
        acc6.x += ev.x*x6.x; acc6.y += ev.y*x6.y; acc6.z += ev.z*x6.z; acc6.w += ev.w*x6.w;
        acc7.x += ev.x*x7.x; acc7.y += ev.y*x7.y; acc7.z += ev.z*x7.z; acc7.w += ev.w*x7.w;
    }
    {
        float s[RTB] = {
            acc0.x+acc0.y+acc0.z+acc0.w, acc1.x+acc1.y+acc1.z+acc1.w,
            acc2.x+acc2.y+acc2.z+acc2.w, acc3.x+acc3.y+acc3.z+acc3.w,
            acc4.x+acc4.y+acc4.z+acc4.w, acc5.x+acc5.y+acc5.z+acc5.w,
            acc6.x+acc6.y+acc6.z+acc6.w, acc7.x+acc7.y+acc7.z+acc7.w };
        #pragma unroll
        for (int t = 0; t < RTB; t++) {
            float v = s[t];
            v += __shfl_xor(v, 1);
            v += __shfl_xor(v, 2);
            v += __shfl_xor(v, 4);
            if (sub == 0) gs[t][e] = 1.f / (1.f + expf(-v));
        }
    }
    __syncthreads();

    // top-4: token = tid>>5, lane e2 = tid&31; butterfly argmax width 32
    {
        int t = tid >> 5, e2 = tid & 31;
        int tok = tile0 + t;
        if (tok < ntok) {
            float v = gs[t][e2];
            #pragma unroll
            for (int r = 0; r < TOPK; r++) {
                float bv = v; int bi = e2;
                #pragma unroll
                for (int sft = 16; sft >= 1; sft >>= 1) {
                    float ov = __shfl_xor(bv, sft, 32);
                    int   oi = __shfl_xor(bi, sft, 32);
                    if (ov > bv || (ov == bv && oi < bi)) { bv = ov; bi = oi; }
                }
                if (e2 == bi) v = -1e30f;            // exclude winner
                if (e2 == r) {                        // lane r commits round r
                    sel_e[(size_t)tok * TOPK + r] = (unsigned)bi;
                    sel_g[(size_t)tok * TOPK + r] = bv;
                }
            }
        }
    }

    // x -> bf16 from LDS (coalesced)
    {
        int navail = min(RTB, ntok - tile0) * (DMODEL / 4);
        ushort4* dst = (ushort4*)(xb + (size_t)tile0 * DMODEL);
        const float4* srcl = (const float4*)&xs[0][0];
        for (int i = tid; i < navail; i += 256) {
            float4 v = srcl[i];
            ushort4 o;
            o.x = f2b(v.x); o.y = f2b(v.y); o.z = f2b(v.z); o.w = f2b(v.w);
            dst[i] = o;
        }
    }
}

// ------- phase B1: per-block expert histogram -------
__global__ __launch_bounds__(256) void hist_k(
    const unsigned int* __restrict__ sel_e, int* __restrict__ ghist, int nsel)
{
    __shared__ int h[NEXP];
    int tid = threadIdx.x;
    if (tid < NEXP) h[tid] = 0;
    __syncthreads();
    int chunk = (nsel + gridDim.x - 1) / gridDim.x;
    int i0 = blockIdx.x * chunk, i1 = min(i0 + chunk, nsel);
    for (int i = i0 + tid; i < i1; i += 256)
        atomicAdd(&h[sel_e[i]], 1);
    __syncthreads();
    if (tid < NEXP) ghist[blockIdx.x * NEXP + tid] = h[tid];
}

// ------- phase B2: prefix over blocks per expert + base + tile list -------
__global__ __launch_bounds__(64) void scan2_k(
    const int* __restrict__ ghist, int* __restrict__ goff,
    int* __restrict__ counts, int* __restrict__ base,
    int* __restrict__ tiles, int* __restrict__ ntiles, int nb)
{
    int e = threadIdx.x;
    if (e < NEXP) {
        int s = 0;
        for (int b = 0; b < nb; b++) {
            goff[b * NEXP + e] = s;
            s += ghist[b * NEXP + e];
        }
        counts[e] = s;
    }
    __syncthreads();
    if (e == 0) {
        int s = 0, nt = 0;
        for (int e2 = 0; e2 < NEXP; e2++) {
            base[e2] = s;
            int c = counts[e2];
            for (int t0 = 0; t0 < c; t0 += MT) tiles[nt++] = (e2 << 8) | (t0 / MT);
            s += c;
        }
        *ntiles = nt;
    }
}

// ------- phase B3: scatter into lists (LDS counters seeded by goff) -------
__global__ __launch_bounds__(256) void scat_k(
    const unsigned int* __restrict__ sel_e, const float* __restrict__ sel_g,
    const int* __restrict__ goff,
    int* __restrict__ tok_list, float* __restrict__ gate_list,
    unsigned int* __restrict__ slotinfo, int nsel, int ntok)
{
    __shared__ int c[NEXP];
    int tid = threadIdx.x;
    if (tid < NEXP) c[tid] = goff[blockIdx.x * NEXP + tid];
    __syncthreads();
    int chunk = (nsel + gridDim.x - 1) / gridDim.x;
    int i0 = blockIdx.x * chunk, i1 = min(i0 + chunk, nsel);
    for (int i = i0 + tid; i < i1; i += 256) {
        unsigned int e = sel_e[i];
        float g = sel_g[i];
        int pos = atomicAdd(&c[e], 1);
        tok_list [(size_t)e * ntok + pos] = i >> 2;
        gate_list[(size_t)e * ntok + pos] = g;
        slotinfo[i] = (e << 16) | (unsigned)pos;
    }
}

// ------- prep: transpose+convert  src[e][R][C] f32  ->  dst[e][C][R] bf16 -------
__global__ __launch_bounds__(256) void prep_t(const float* __restrict__ src,
                                              unsigned short* __restrict__ dst,
                                              int R, int C) {
    __shared__ float tile[64][65];
    int e  = blockIdx.z;
    int r0 = blockIdx.y * 64, c0 = blockIdx.x * 64;
    const float* s = src + (size_t)e * R * C;
    unsigned short* d = dst + (size_t)e * R * C;
    for (int i = 0; i < 16; i++) {
        int c = i * 256 + threadIdx.x;
        int rr = c >> 6, cc = c & 63;
        tile[rr][cc] = s[(size_t)(r0 + rr) * C + c0 + cc];
    }
    __syncthreads();
    for (int i = 0; i < 16; i++) {
        int c = i * 256 + threadIdx.x;
        int wr = c >> 6, wc = c & 63;
        d[(size_t)(c0 + wr) * R + r0 + wc] = f2b(tile[wc][wr]);
    }
}

// ---- GEMM1: hs[slot][f] = relu(x . K_e) * gate  (single-buffer, 2-barrier) ----
__global__ __launch_bounds__(256) void gemm1_k(
    const unsigned short* __restrict__ xb,
    const unsigned short* __restrict__ kt,   // [E][512 f][1024 d]
    const int* __restrict__ counts, const int* __restrict__ base,
    const int* __restrict__ tiles, const int* __restrict__ ntiles,
    const int* __restrict__ tok_list, const float* __restrict__ gate_list,
    unsigned short* __restrict__ hs, int ntok)
{
    int ti = blockIdx.x;
    if (ti >= *ntiles) return;
    int code = tiles[ti];
    int e = code >> 8, t0 = (code & 255) * MT;
    int cnt  = counts[e];
    int f0   = blockIdx.y * NT;
    int live = min(MT, cnt - t0);

    __shared__ unsigned short Xs[MT * PITCH];   // 10 KB
    __shared__ unsigned short Ks[NT * PITCH];   // 10 KB
    __shared__ int   toks[MT];
    __shared__ float gts[MT];

    int tid = threadIdx.x, lane = tid & 63, w = tid >> 6;
    int lr = lane & 15, lg = lane >> 4;

    if (tid < MT) {
        bool lv = tid < live;
        toks[tid] = lv ? tok_list [(size_t)e * ntok + t0 + tid] : 0;
        gts[tid]  = lv ? gate_list[(size_t)e * ntok + t0 + tid] : 0.f;
    }
    __syncthreads();

    int r0 = tid >> 2, q = tid & 3;
    const unsigned short* ke  = kt + (size_t)e * FDIM * DMODEL + (size_t)f0 * DMODEL;
    const unsigned short* xp0 = xb + (size_t)toks[r0]      * DMODEL + q * 8;
    const unsigned short* xp1 = xb + (size_t)toks[64 + r0] * DMODEL + q * 8;
    const unsigned short* kp0 = ke + (size_t)r0        * DMODEL + q * 8;
    const unsigned short* kp1 = ke + (size_t)(64 + r0) * DMODEL + q * 8;
    int wa0 = r0 * PITCH + q * 8, wa1 = (64 + r0) * PITCH + q * 8;

    f32x4 acc[8][2];
    #pragma unroll
    for (int m = 0; m < 8; m++)
        #pragma unroll
        for (int n = 0; n < 2; n++)
            acc[m][n] = (f32x4){0.f, 0.f, 0.f, 0.f};

    for (int k0 = 0; k0 < DMODEL; k0 += BK) {
        // stage tile k0 (global -> reg -> LDS), single buffer
        short8 a0 = *(const short8*)(xp0 + k0);
        short8 a1 = *(const short8*)(xp1 + k0);
        short8 b0 = *(const short8*)(kp0 + k0);
        short8 b1 = *(const short8*)(kp1 + k0);
        *(short8*)(Xs + wa0) = a0; *(short8*)(Xs + wa1) = a1;
        *(short8*)(Ks + wa0) = b0; *(short8*)(Ks + wa1) = b1;
        __syncthreads();
        short8 a[8];
        #pragma unroll
        for (int m = 0; m < 8; m++)
            a[m] = *(const short8*)(Xs + (m * 16 + lr) * PITCH + lg * 8);
        #pragma unroll
        for (int n = 0; n < 2; n++) {
            short8 b = *(const short8*)(Ks + (w * 32 + n * 16 + lr) * PITCH + lg * 8);
            #pragma unroll
            for (int m = 0; m < 8; m++)
                acc[m][n] = __builtin_amdgcn_mfma_f32_16x16x32_bf16(a[m], b, acc[m][n], 0, 0, 0);
        }
        __syncthreads();
    }

    int hb = base[e] + t0;
    #pragma unroll
    for (int m = 0; m < 8; m++) {
        #pragma unroll
        for (int n = 0; n < 2; n++) {
            int col = f0 + w * 32 + n * 16 + lr;
            #pragma unroll
            for (int r = 0; r < 4; r++) {
                int row = m * 16 + lg * 4 + r;
                if (row < live)
                    hs[(size_t)(hb + row) * FDIM + col] = f2b(fmaxf(acc[m][n][r], 0.f) * gts[row]);
            }
        }
    }
}

// ---- GEMM2: ys[slot][v] = hs[slot] . V_e  (single-buffer, 2-barrier) ----
__global__ __launch_bounds__(256) void gemm2_k(
    const unsigned short* __restrict__ hs,
    const unsigned short* __restrict__ vt,   // [E][1024 v][512 f]
    const int* __restrict__ counts, const int* __restrict__ base,
    const int* __restrict__ tiles, const int* __restrict__ ntiles,
    float* __restrict__ ys)
{
    int ti = blockIdx.x;
    if (ti >= *ntiles) return;
    int code = tiles[ti];
    int e = code >> 8, t0 = (code & 255) * MT;
    int cnt  = counts[e];
    int v0   = blockIdx.y * NT;
    int live = min(MT, cnt - t0);
    int hb   = base[e] + t0;

    __shared__ unsigned short Hs[MT * PITCH];
    __shared__ unsigned short Vs[NT * PITCH];

    int tid = threadIdx.x, lane = tid & 63, w = tid >> 6;
    int lr = lane & 15, lg = lane >> 4;

    int r0 = tid >> 2, q = tid & 3;
    const unsigned short* he  = hs + (size_t)hb * FDIM;
    const unsigned short* ve  = vt + (size_t)e * DMODEL * FDIM + (size_t)v0 * FDIM;
    const unsigned short* hp0 = he + (size_t)r0        * FDIM + q * 8;
    const unsigned short* hp1 = he + (size_t)(64 + r0) * FDIM + q * 8;   // may over-read slack
    const unsigned short* vp0 = ve + (size_t)r0        * FDIM + q * 8;
    const unsigned short* vp1 = ve + (size_t)(64 + r0) * FDIM + q * 8;
    int wa0 = r0 * PITCH + q * 8, wa1 = (64 + r0) * PITCH + q * 8;

    f32x4 acc[8][2];
    #pragma unroll
    for (int m = 0; m < 8; m++)
        #pragma unroll
        for (int n = 0; n < 2; n++)
            acc[m][n] = (f32x4){0.f, 0.f, 0.f, 0.f};

    for (int k0 = 0; k0 < FDIM; k0 += BK) {
        short8 a0 = *(const short8*)(hp0 + k0);
        short8 a1 = *(const short8*)(hp1 + k0);
        short8 b0 = *(const short8*)(vp0 + k0);
        short8 b1 = *(const short8*)(vp1 + k0);
        *(short8*)(Hs + wa0) = a0; *(short8*)(Hs + wa1) = a1;
        *(short8*)(Vs + wa0) = b0; *(short8*)(Vs + wa1) = b1;
        __syncthreads();
        short8 a[8];
        #pragma unroll
        for (int m = 0; m < 8; m++)
            a[m] = *(const short8*)(Hs + (m * 16 + lr) * PITCH + lg * 8);
        #pragma unroll
        for (int n = 0; n < 2; n++) {
            short8 b = *(const short8*)(Vs + (w * 32 + n * 16 + lr) * PITCH + lg * 8);
            #pragma unroll
            for (int m = 0; m < 8; m++)
                acc[m][n] = __builtin_amdgcn_mfma_f32_16x16x32_bf16(a[m], b, acc[m][n], 0, 0, 0);
        }
        __syncthreads();
    }

    #pragma unroll
    for (int m = 0; m < 8; m++) {
        #pragma unroll
        for (int n = 0; n < 2; n++) {
            int col = v0 + w * 32 + n * 16 + lr;
            #pragma unroll
            for (int r = 0; r < 4; r++) {
                int row = m * 16 + lg * 4 + r;
                if (row < live)
                    ys[(size_t)(hb + row) * DMODEL + col] = acc[m][n][r];
            }
        }
    }
}

// ---------------- combine: out[tok] = sum of the token's 4 slot rows ----------------
__global__ __launch_bounds__(256) void combine_k(
    const float* __restrict__ ys, const unsigned int* __restrict__ slotinfo,
    const int* __restrict__ base, float* __restrict__ out)
{
    int tok = blockIdx.x;
    unsigned int s0 = slotinfo[(size_t)tok * TOPK + 0];
    unsigned int s1 = slotinfo[(size_t)tok * TOPK + 1];
    unsigned int s2 = slotinfo[(size_t)tok * TOPK + 2];
    unsigned int s3 = slotinfo[(size_t)tok * TOPK + 3];
    const float4* y0 = (const float4*)(ys + (size_t)(base[s0 >> 16] + (s0 & 0xFFFF)) * DMODEL);
    const float4* y1 = (const float4*)(ys + (size_t)(base[s1 >> 16] + (s1 & 0xFFFF)) * DMODEL);
    const float4* y2 = (const float4*)(ys + (size_t)(base[s2 >> 16] + (s2 & 0xFFFF)) * DMODEL);
    const float4* y3 = (const float4*)(ys + (size_t)(base[s3 >> 16] + (s3 & 0xFFFF)) * DMODEL);
    int i = threadIdx.x;
    float4 a = y0[i], b = y1[i], c = y2[i], d = y3[i];
    float4 o;
    o.x = a.x + b.x + c.x + d.x;
    o.y = a.y + b.y + c.y + d.y;
    o.z = a.z + b.z + c.z + d.z;
    o.w = a.w + b.w + c.w + d.w;
    ((float4*)(out + (size_t)tok * DMODEL))[i] = o;
}

// ---------------- fp32 fallback (only if workspace too small) ----------------
#define BTF 16
__global__ __launch_bounds__(256) void expert_k(
    const float* __restrict__ x, const float* __restrict__ keys,
    const float* __restrict__ values, const int* __restrict__ counts,
    const int* __restrict__ tok_list, const float* __restrict__ gate_list,
    float* __restrict__ out, int ntok)
{
    int e   = blockIdx.y;
    int cnt = counts[e];
    int t0  = blockIdx.x * BTF;
    if (t0 >= cnt) return;
    int nt = (cnt - t0 < BTF) ? (cnt - t0) : BTF;

    __shared__ float xs[BTF][DMODEL];
    __shared__ float hsl[BTF][FDIM];
    __shared__ int   toks[BTF];
    __shared__ float gts[BTF];

    if (threadIdx.x < BTF) {
        int t = threadIdx.x;
        bool live = (t < nt);
        toks[t] = live ? tok_list [(size_t)e * ntok + t0 + t] : 0;
        gts[t]  = live ? gate_list[(size_t)e * ntok + t0 + t] : 0.f;
    }
    __syncthreads();
    for (int i = threadIdx.x; i < BTF * (DMODEL / 4); i += 256) {
        int r = i >> 8, c = i & 255;
        ((float4*)xs[r])[c] = ((const float4*)(x + (size_t)toks[r] * DMODEL))[c];
    }
    __syncthreads();

    {
        int f = threadIdx.x * 2;
        float acc0[BTF], acc1[BTF];
        #pragma unroll
        for (int t = 0; t < BTF; t++) { acc0[t] = 0.f; acc1[t] = 0.f; }
        const float* kp = keys + (size_t)e * DMODEL * FDIM + f;
        for (int k = 0; k < DMODEL; k += 4) {
            const float* kr = kp + (size_t)k * FDIM;
            float2 kv0 = *(const float2*)(kr);
            float2 kv1 = *(const float2*)(kr + FDIM);
            float2 kv2 = *(const float2*)(kr + 2 * FDIM);
            float2 kv3 = *(const float2*)(kr + 3 * FDIM);
            #pragma unroll
            for (int t = 0; t < BTF; t++) {
                float4 xv = *(const float4*)(&xs[t][k]);
                acc0[t] += xv.x * kv0.x + xv.y * kv1.x + xv.z * kv2.x + xv.w * kv3.x;
                acc1[t] += xv.x * kv0.y + xv.y * kv1.y + xv.z * kv2.y + xv.w * kv3.y;
            }
        }
        #pragma unroll
        for (int t = 0; t < BTF; t++) {
            float g = gts[t];
            hsl[t][f]     = fmaxf(acc0[t], 0.f) * g;
            hsl[t][f + 1] = fmaxf(acc1[t], 0.f) * g;
        }
    }
    __syncthreads();

    {
        int v = threadIdx.x * 4;
        float acc[BTF][4];
        #pragma unroll
        for (int t = 0; t < BTF; t++) { acc[t][0]=0.f; acc[t][1]=0.f; acc[t][2]=0.f; acc[t][3]=0.f; }
        const float* vp = values + (size_t)e * FDIM * DMODEL + v;
        for (int k = 0; k < FDIM; k += 2) {
            float4 va0 = *(const float4*)(vp + (size_t)k * DMODEL);
            float4 va1 = *(const float4*)(vp + (size_t)(k + 1) * DMODEL);
            #pragma unroll
            for (int t = 0; t < BTF; t++) {
                float2 hv = *(const float2*)(&hsl[t][k]);
                acc[t][0] += hv.x * va0.x + hv.y * va1.x;
                acc[t][1] += hv.x * va0.y + hv.y * va1.y;
                acc[t][2] += hv.x * va0.z + hv.y * va1.z;
                acc[t][3] += hv.x * va0.w + hv.y * va1.w;
            }
        }
        #pragma unroll
        for (int t = 0; t < BTF; t++) {
            if (t < nt) {
                float* orow = out + (size_t)toks[t] * DMODEL + v;
                atomicAdd(orow + 0, acc[t][0]);
                atomicAdd(orow + 1, acc[t][1]);
                atomicAdd(orow + 2, acc[t][2]);
                atomicAdd(orow + 3, acc[t][3]);
            }
        }
    }
}

extern "C" void kernel_launch(void* const* d_in, const int* in_sizes, int n_in,
                              void* d_out, int out_size, void* d_ws, size_t ws_size,
                              hipStream_t stream) {
    const float* x      = (const float*)d_in[0];
    const float* esel   = (const float*)d_in[1];
    const float* keys   = (const float*)d_in[2];
    const float* values = (const float*)d_in[3];
    float* out = (float*)d_out;
    int ntok = in_sizes[0] / DMODEL;

    // workspace layout
    const size_t OFF_BASE = 512;          // 32 ints
    const size_t OFF_NT   = 1024;         // 1 int
    const size_t OFF_TILE = 2048;         // <= MAXT ints
    const size_t OFF_HIST = 16 << 10;     // NBORD*NEXP ints (8 KB)
    const size_t OFF_GOFF = 32 << 10;     // NBORD*NEXP ints (8 KB)
    const size_t OFF_SLOT = 64 << 10;     // ntok*4 uints (64 KB @ ntok=4096)
    const size_t OFF_SELE = 128 << 10;    // ntok*4 uints (64 KB)
    const size_t OFF_SELG = 192 << 10;    // ntok*4 floats (64 KB)
    const size_t OFF_TOK  = 256 << 10;    // NEXP*ntok ints (512 KB)
    const size_t OFF_GATE = 1ull << 20;   // NEXP*ntok floats (512 KB)
    const size_t OFF_XB   = 2ull << 20;   // ntok*1024 bf16 (8.4 MB)
    const size_t OFF_KT   = 12ull << 20;  // 33.6 MB
    const size_t OFF_VT   = 46ull << 20;  // 33.6 MB
    const size_t OFF_HS   = 80ull << 20;  // (ntok*4+MT)*512 bf16 (~17 MB)
    const size_t OFF_YS   = 98ull << 20;  // ntok*4*1024 f32 (~67 MB)
    const size_t NEED     = OFF_YS + (size_t)ntok * TOPK * DMODEL * sizeof(float) + (1 << 20);

    int*      counts    = (int*)d_ws;
    int*      ebase     = (int*)((char*)d_ws + OFF_BASE);
    int*      ntiles    = (int*)((char*)d_ws + OFF_NT);
    int*      tiles     = (int*)((char*)d_ws + OFF_TILE);
    int*      ghist     = (int*)((char*)d_ws + OFF_HIST);
    int*      goff      = (int*)((char*)d_ws + OFF_GOFF);
    unsigned* slotinfo  = (unsigned*)((char*)d_ws + OFF_SLOT);
    unsigned* sel_e     = (unsigned*)((char*)d_ws + OFF_SELE);
    float*    sel_g     = (float*)((char*)d_ws + OFF_SELG);
    int*      tok_list  = (int*)((char*)d_ws + OFF_TOK);
    float*    gate_list = (float*)((char*)d_ws + OFF_GATE);
    unsigned short* xb  = (unsigned short*)((char*)d_ws + OFF_XB);

    int nsel = ntok * TOPK;
    int rblocks = (ntok + RTB - 1) / RTB;
    route_a<<<rblocks, 256, 0, stream>>>(x, esel, xb, sel_e, sel_g, ntok);
    hist_k<<<NBORD, 256, 0, stream>>>(sel_e, ghist, nsel);
    scan2_k<<<1, 64, 0, stream>>>(ghist, goff, counts, ebase, tiles, ntiles, NBORD);
    scat_k<<<NBORD, 256, 0, stream>>>(sel_e, sel_g, goff, tok_list, gate_list,
                                      slotinfo, nsel, ntok);

    if (ws_size >= NEED) {
        unsigned short* kt = (unsigned short*)((char*)d_ws + OFF_KT);
        unsigned short* vt = (unsigned short*)((char*)d_ws + OFF_VT);
        unsigned short* hs = (unsigned short*)((char*)d_ws + OFF_HS);
        float*          ys = (float*)((char*)d_ws + OFF_YS);

        prep_t<<<dim3(FDIM / 64, DMODEL / 64, NEXP), 256, 0, stream>>>(keys,   kt, DMODEL, FDIM);
        prep_t<<<dim3(DMODEL / 64, FDIM / 64, NEXP), 256, 0, stream>>>(values, vt, FDIM, DMODEL);

        int maxt = (ntok * TOPK + MT - 1) / MT + NEXP;   // worst-case live tiles
        gemm1_k<<<dim3(maxt, FDIM / NT), 256, 0, stream>>>(
            xb, kt, counts, ebase, tiles, ntiles, tok_list, gate_list, hs, ntok);
        gemm2_k<<<dim3(maxt, DMODEL / NT), 256, 0, stream>>>(
            hs, vt, counts, ebase, tiles, ntiles, ys);
        combine_k<<<ntok, 256, 0, stream>>>(ys, slotinfo, ebase, out);
    } else {
        hipMemsetAsync(out, 0, (size_t)out_size * sizeof(float), stream);
        int ntiles2 = (ntok + BTF - 1) / BTF;
        expert_k<<<dim3(ntiles2, NEXP), 256, 0, stream>>>(
            x, keys, values, counts, tok_list, gate_list, out, ntok);
    }
}

// Round 14
// 202.212 us; speedup vs baseline: 1.0451x; 1.0451x over previous
//
#include <hip/hip_runtime.h>

#define DMODEL 1024
#define NEXP   32
#define FDIM   512
#define TOPK   4

#define MT    128   // token tile
#define NT    128   // f / v tile
#define BK    32
#define RTB   8     // tokens per routing block
#define NBORD 64    // blocks for hist/scatter phases

using short8 = __attribute__((ext_vector_type(8))) short;
using f32x4  = __attribute__((ext_vector_type(4))) float;

#define AS1 __attribute__((address_space(1)))
#define AS3 __attribute__((address_space(3)))
__device__ __forceinline__ void gload_lds16(const void* g, void* l) {
    // async global->LDS DMA, 16B/lane; LDS dest = (uniform base) + lane*16
    __builtin_amdgcn_global_load_lds((const AS1 unsigned int*)g, (AS3 unsigned int*)l, 16, 0, 0);
}

__device__ __forceinline__ unsigned short f2b(float f) {
    unsigned int u = __float_as_uint(f);
    unsigned int r = (u + 0x7FFFu + ((u >> 16) & 1u)) >> 16;   // RNE bf16
    return (unsigned short)r;
}

// ------- phase A: gates + top-4 -> sel arrays (NO atomics) + x->bf16 -------
__global__ __launch_bounds__(256) void route_a(
    const float* __restrict__ x, const float* __restrict__ esel,
    unsigned short* __restrict__ xb,
    unsigned int* __restrict__ sel_e, float* __restrict__ sel_g, int ntok)
{
    int tile0 = blockIdx.x * RTB;
    int tid = threadIdx.x;

    __shared__ float xs[RTB][DMODEL];   // 32 KB
    __shared__ float gs[RTB][NEXP];     // 1 KB

    {
        const float4* src = (const float4*)(x + (size_t)tile0 * DMODEL);
        float4* dst = (float4*)&xs[0][0];
        int navail = min(RTB, ntok - tile0) * (DMODEL / 4);
        for (int i = tid; i < RTB * (DMODEL / 4); i += 256)
            dst[i] = src[i < navail ? i : 0];
    }
    __syncthreads();

    int e = tid >> 3, sub = tid & 7;
    float4 acc0 = {0,0,0,0}, acc1 = {0,0,0,0}, acc2 = {0,0,0,0}, acc3 = {0,0,0,0};
    float4 acc4 = {0,0,0,0}, acc5 = {0,0,0,0}, acc6 = {0,0,0,0}, acc7 = {0,0,0,0};
    const float* er = esel + (size_t)e * DMODEL + sub * 4;
    #pragma unroll 4
    for (int j = 0; j < DMODEL / 32; j++) {
        float4 ev = *(const float4*)(er + j * 32);
        int kk = sub * 4 + j * 32;
        float4 x0 = *(const float4*)(&xs[0][kk]);
        float4 x1 = *(const float4*)(&xs[1][kk]);
        float4 x2 = *(const float4*)(&xs[2][kk]);
        float4 x3 = *(const float4*)(&xs[3][kk]);
        float4 x4 = *(const float4*)(&xs[4][kk]);
        float4 x5 = *(const float4*)(&xs[5][kk]);
        float4 x6 = *(const float4*)(&xs[6][kk]);
        float4 x7 = *(const float4*)(&xs[7][kk]);
        acc0.x += ev.x*x0.x; acc0.y += ev.y*x0.y; acc0.z += ev.z*x0.z; acc0.w += ev.w*x0.w;
        acc1.x += ev.x*x1.x; acc1.y += ev.y*x1.y; acc1.z += ev.z*x1.z; acc1.w += ev.w*x1.w;
        acc2.x += ev.x*x2.x; acc2.y += ev.y*x2.y; acc2.z += ev.z*x2.z; acc2.w += ev.w*x2.w;
        acc3.x += ev.x*x3.x; acc3.y += ev.y*x3.y; acc3.z += ev.z*x3.z; acc3.w += ev.w*x3.w;
        acc4.x += ev.x*x4.x; acc4.y += ev.y*x4.y; acc4.z += ev.z*x4.z; acc4.w += ev.w*x4.w;
        acc5.x += ev.x*x5.x; acc5.y += ev.y*x5.y; acc5.z += ev.z*x5.z; acc5.w += ev.w*x5.w;
        acc6.x += ev.x*x6.x; acc6.y += ev.y*x6.y; acc6.z += ev.z*x6.z; acc6.w += ev.w*x6.w;
        acc7.x += ev.x*x7.x; acc7.y += ev.y*x7.y; acc7.z += ev.z*x7.z; acc7.w += ev.w*x7.w;
    }
    {
        float s[RTB] = {
            acc0.x+acc0.y+acc0.z+acc0.w, acc1.x+acc1.y+acc1.z+acc1.w,
            acc2.x+acc2.y+acc2.z+acc2.w, acc3.x+acc3.y+acc3.z+acc3.w,
            acc4.x+acc4.y+acc4.z+acc4.w, acc5.x+acc5.y+acc5.z+acc5.w,
            acc6.x+acc6.y+acc6.z+acc6.w, acc7.x+acc7.y+acc7.z+acc7.w };
        #pragma unroll
        for (int t = 0; t < RTB; t++) {
            float v = s[t];
            v += __shfl_xor(v, 1);
            v += __shfl_xor(v, 2);
            v += __shfl_xor(v, 4);
            if (sub == 0) gs[t][e] = 1.f / (1.f + expf(-v));
        }
    }
    __syncthreads();

    {
        int t = tid >> 5, e2 = tid & 31;
        int tok = tile0 + t;
        if (tok < ntok) {
            float v = gs[t][e2];
            #pragma unroll
            for (int r = 0; r < TOPK; r++) {
                float bv = v; int bi = e2;
                #pragma unroll
                for (int sft = 16; sft >= 1; sft >>= 1) {
                    float ov = __shfl_xor(bv, sft, 32);
                    int   oi = __shfl_xor(bi, sft, 32);
                    if (ov > bv || (ov == bv && oi < bi)) { bv = ov; bi = oi; }
                }
                if (e2 == bi) v = -1e30f;
                if (e2 == r) {
                    sel_e[(size_t)tok * TOPK + r] = (unsigned)bi;
                    sel_g[(size_t)tok * TOPK + r] = bv;
                }
            }
        }
    }

    {
        int navail = min(RTB, ntok - tile0) * (DMODEL / 4);
        ushort4* dst = (ushort4*)(xb + (size_t)tile0 * DMODEL);
        const float4* srcl = (const float4*)&xs[0][0];
        for (int i = tid; i < navail; i += 256) {
            float4 v = srcl[i];
            ushort4 o;
            o.x = f2b(v.x); o.y = f2b(v.y); o.z = f2b(v.z); o.w = f2b(v.w);
            dst[i] = o;
        }
    }
}

// ------- phase B1: per-block expert histogram -------
__global__ __launch_bounds__(256) void hist_k(
    const unsigned int* __restrict__ sel_e, int* __restrict__ ghist, int nsel)
{
    __shared__ int h[NEXP];
    int tid = threadIdx.x;
    if (tid < NEXP) h[tid] = 0;
    __syncthreads();
    int chunk = (nsel + gridDim.x - 1) / gridDim.x;
    int i0 = blockIdx.x * chunk, i1 = min(i0 + chunk, nsel);
    for (int i = i0 + tid; i < i1; i += 256)
        atomicAdd(&h[sel_e[i]], 1);
    __syncthreads();
    if (tid < NEXP) ghist[blockIdx.x * NEXP + tid] = h[tid];
}

// ------- phase B2: prefix over blocks per expert + base + tile list -------
__global__ __launch_bounds__(64) void scan2_k(
    const int* __restrict__ ghist, int* __restrict__ goff,
    int* __restrict__ counts, int* __restrict__ base,
    int* __restrict__ tiles, int* __restrict__ ntiles, int nb)
{
    int e = threadIdx.x;
    if (e < NEXP) {
        int s = 0;
        for (int b = 0; b < nb; b++) {
            goff[b * NEXP + e] = s;
            s += ghist[b * NEXP + e];
        }
        counts[e] = s;
    }
    __syncthreads();
    if (e == 0) {
        int s = 0, nt = 0;
        for (int e2 = 0; e2 < NEXP; e2++) {
            base[e2] = s;
            int c = counts[e2];
            for (int t0 = 0; t0 < c; t0 += MT) tiles[nt++] = (e2 << 8) | (t0 / MT);
            s += c;
        }
        *ntiles = nt;
    }
}

// ------- phase B3: scatter into lists (LDS counters seeded by goff) -------
__global__ __launch_bounds__(256) void scat_k(
    const unsigned int* __restrict__ sel_e, const float* __restrict__ sel_g,
    const int* __restrict__ goff,
    int* __restrict__ tok_list, float* __restrict__ gate_list,
    unsigned int* __restrict__ slotinfo, int nsel, int ntok)
{
    __shared__ int c[NEXP];
    int tid = threadIdx.x;
    if (tid < NEXP) c[tid] = goff[blockIdx.x * NEXP + tid];
    __syncthreads();
    int chunk = (nsel + gridDim.x - 1) / gridDim.x;
    int i0 = blockIdx.x * chunk, i1 = min(i0 + chunk, nsel);
    for (int i = i0 + tid; i < i1; i += 256) {
        unsigned int e = sel_e[i];
        float g = sel_g[i];
        int pos = atomicAdd(&c[e], 1);
        tok_list [(size_t)e * ntok + pos] = i >> 2;
        gate_list[(size_t)e * ntok + pos] = g;
        slotinfo[i] = (e << 16) | (unsigned)pos;
    }
}

// ------- prep: transpose+convert  src[e][R][C] f32  ->  dst[e][C][R] bf16 -------
__global__ __launch_bounds__(256) void prep_t(const float* __restrict__ src,
                                              unsigned short* __restrict__ dst,
                                              int R, int C) {
    __shared__ float tile[64][65];
    int e  = blockIdx.z;
    int r0 = blockIdx.y * 64, c0 = blockIdx.x * 64;
    const float* s = src + (size_t)e * R * C;
    unsigned short* d = dst + (size_t)e * R * C;
    for (int i = 0; i < 16; i++) {
        int c = i * 256 + threadIdx.x;
        int rr = c >> 6, cc = c & 63;
        tile[rr][cc] = s[(size_t)(r0 + rr) * C + c0 + cc];
    }
    __syncthreads();
    for (int i = 0; i < 16; i++) {
        int c = i * 256 + threadIdx.x;
        int wr = c >> 6, wc = c & 63;
        d[(size_t)(c0 + wr) * R + r0 + wc] = f2b(tile[wc][wr]);
    }
}

// ---- GEMM1: hs[slot][f] = relu(x . K_e) * gate  (global_load_lds, linear LDS) ----
__global__ __launch_bounds__(256) void gemm1_k(
    const unsigned short* __restrict__ xb,
    const unsigned short* __restrict__ kt,   // [E][512 f][1024 d]
    const int* __restrict__ counts, const int* __restrict__ base,
    const int* __restrict__ tiles, const int* __restrict__ ntiles,
    const int* __restrict__ tok_list, const float* __restrict__ gate_list,
    unsigned short* __restrict__ hs, int ntok)
{
    int ti = blockIdx.x;
    if (ti >= *ntiles) return;
    int code = tiles[ti];
    int e = code >> 8, t0 = (code & 255) * MT;
    int cnt  = counts[e];
    int f0   = blockIdx.y * NT;
    int live = min(MT, cnt - t0);

    __shared__ unsigned short Xs[MT * BK];   // 8 KB, linear [128][32]
    __shared__ unsigned short Ks[NT * BK];   // 8 KB
    __shared__ int   toks[MT];
    __shared__ float gts[MT];

    int tid = threadIdx.x, lane = tid & 63, w = tid >> 6;
    int lr = lane & 15, lg = lane >> 4;

    if (tid < MT) {
        bool lv = tid < live;
        toks[tid] = lv ? tok_list [(size_t)e * ntok + t0 + tid] : 0;
        gts[tid]  = lv ? gate_list[(size_t)e * ntok + t0 + tid] : 0.f;
    }
    __syncthreads();

    // per-lane source rows for this wave's two 1KB chunks (16 rows each)
    int c0c = 2 * w, c1c = 2 * w + 1;
    int rowA = c0c * 16 + (lane >> 2);
    int rowB = c1c * 16 + (lane >> 2);
    int qq   = (lane & 3) * 8;               // ushort offset within row
    const unsigned short* ke = kt + (size_t)e * FDIM * DMODEL + (size_t)f0 * DMODEL;
    const unsigned short* sx0 = xb + (size_t)toks[rowA] * DMODEL + qq;
    const unsigned short* sx1 = xb + (size_t)toks[rowB] * DMODEL + qq;
    const unsigned short* sk0 = ke + (size_t)rowA * DMODEL + qq;
    const unsigned short* sk1 = ke + (size_t)rowB * DMODEL + qq;
    unsigned short* dx0 = Xs + c0c * 512;    // uniform per wave
    unsigned short* dx1 = Xs + c1c * 512;
    unsigned short* dk0 = Ks + c0c * 512;
    unsigned short* dk1 = Ks + c1c * 512;

    f32x4 acc[8][2];
    #pragma unroll
    for (int m = 0; m < 8; m++)
        #pragma unroll
        for (int n = 0; n < 2; n++)
            acc[m][n] = (f32x4){0.f, 0.f, 0.f, 0.f};

    for (int k0 = 0; k0 < DMODEL; k0 += BK) {
        gload_lds16(sx0 + k0, dx0);
        gload_lds16(sx1 + k0, dx1);
        gload_lds16(sk0 + k0, dk0);
        gload_lds16(sk1 + k0, dk1);
        __syncthreads();                     // drains vmcnt -> tiles ready
        short8 a[8];
        #pragma unroll
        for (int m = 0; m < 8; m++)
            a[m] = *(const short8*)(Xs + (m * 16 + lr) * BK + lg * 8);
        #pragma unroll
        for (int n = 0; n < 2; n++) {
            short8 b = *(const short8*)(Ks + (w * 32 + n * 16 + lr) * BK + lg * 8);
            #pragma unroll
            for (int m = 0; m < 8; m++)
                acc[m][n] = __builtin_amdgcn_mfma_f32_16x16x32_bf16(a[m], b, acc[m][n], 0, 0, 0);
        }
        __syncthreads();
    }

    int hb = base[e] + t0;
    #pragma unroll
    for (int m = 0; m < 8; m++) {
        #pragma unroll
        for (int n = 0; n < 2; n++) {
            int col = f0 + w * 32 + n * 16 + lr;
            #pragma unroll
            for (int r = 0; r < 4; r++) {
                int row = m * 16 + lg * 4 + r;
                if (row < live)
                    hs[(size_t)(hb + row) * FDIM + col] = f2b(fmaxf(acc[m][n][r], 0.f) * gts[row]);
            }
        }
    }
}

// ---- GEMM2: ys[slot][v] = hs[slot] . V_e  (global_load_lds, linear LDS) ----
__global__ __launch_bounds__(256) void gemm2_k(
    const unsigned short* __restrict__ hs,
    const unsigned short* __restrict__ vt,   // [E][1024 v][512 f]
    const int* __restrict__ counts, const int* __restrict__ base,
    const int* __restrict__ tiles, const int* __restrict__ ntiles,
    float* __restrict__ ys)
{
    int ti = blockIdx.x;
    if (ti >= *ntiles) return;
    int code = tiles[ti];
    int e = code >> 8, t0 = (code & 255) * MT;
    int cnt  = counts[e];
    int v0   = blockIdx.y * NT;
    int live = min(MT, cnt - t0);
    int hb   = base[e] + t0;

    __shared__ unsigned short Hs[MT * BK];   // 8 KB linear
    __shared__ unsigned short Vs[NT * BK];   // 8 KB

    int tid = threadIdx.x, lane = tid & 63, w = tid >> 6;
    int lr = lane & 15, lg = lane >> 4;

    int c0c = 2 * w, c1c = 2 * w + 1;
    int rowA = c0c * 16 + (lane >> 2);
    int rowB = c1c * 16 + (lane >> 2);
    int qq   = (lane & 3) * 8;
    const unsigned short* he = hs + (size_t)hb * FDIM;
    const unsigned short* ve = vt + (size_t)e * DMODEL * FDIM + (size_t)v0 * FDIM;
    const unsigned short* sh0 = he + (size_t)rowA * FDIM + qq;   // may over-read slack
    const unsigned short* sh1 = he + (size_t)rowB * FDIM + qq;
    const unsigned short* sv0 = ve + (size_t)rowA * FDIM + qq;
    const unsigned short* sv1 = ve + (size_t)rowB * FDIM + qq;
    unsigned short* dh0 = Hs + c0c * 512;
    unsigned short* dh1 = Hs + c1c * 512;
    unsigned short* dv0 = Vs + c0c * 512;
    unsigned short* dv1 = Vs + c1c * 512;

    f32x4 acc[8][2];
    #pragma unroll
    for (int m = 0; m < 8; m++)
        #pragma unroll
        for (int n = 0; n < 2; n++)
            acc[m][n] = (f32x4){0.f, 0.f, 0.f, 0.f};

    for (int k0 = 0; k0 < FDIM; k0 += BK) {
        gload_lds16(sh0 + k0, dh0);
        gload_lds16(sh1 + k0, dh1);
        gload_lds16(sv0 + k0, dv0);
        gload_lds16(sv1 + k0, dv1);
        __syncthreads();
        short8 a[8];
        #pragma unroll
        for (int m = 0; m < 8; m++)
            a[m] = *(const short8*)(Hs + (m * 16 + lr) * BK + lg * 8);
        #pragma unroll
        for (int n = 0; n < 2; n++) {
            short8 b = *(const short8*)(Vs + (w * 32 + n * 16 + lr) * BK + lg * 8);
            #pragma unroll
            for (int m = 0; m < 8; m++)
                acc[m][n] = __builtin_amdgcn_mfma_f32_16x16x32_bf16(a[m], b, acc[m][n], 0, 0, 0);
        }
        __syncthreads();
    }

    #pragma unroll
    for (int m = 0; m < 8; m++) {
        #pragma unroll
        for (int n = 0; n < 2; n++) {
            int col = v0 + w * 32 + n * 16 + lr;
            #pragma unroll
            for (int r = 0; r < 4; r++) {
                int row = m * 16 + lg * 4 + r;
                if (row < live)
                    ys[(size_t)(hb + row) * DMODEL + col] = acc[m][n][r];
            }
        }
    }
}

// ---------------- combine: out[tok] = sum of the token's 4 slot rows ----------------
__global__ __launch_bounds__(256) void combine_k(
    const float* __restrict__ ys, const unsigned int* __restrict__ slotinfo,
    const int* __restrict__ base, float* __restrict__ out)
{
    int tok = blockIdx.x;
    unsigned int s0 = slotinfo[(size_t)tok * TOPK + 0];
    unsigned int s1 = slotinfo[(size_t)tok * TOPK + 1];
    unsigned int s2 = slotinfo[(size_t)tok * TOPK + 2];
    unsigned int s3 = slotinfo[(size_t)tok * TOPK + 3];
    const float4* y0 = (const float4*)(ys + (size_t)(base[s0 >> 16] + (s0 & 0xFFFF)) * DMODEL);
    const float4* y1 = (const float4*)(ys + (size_t)(base[s1 >> 16] + (s1 & 0xFFFF)) * DMODEL);
    const float4* y2 = (const float4*)(ys + (size_t)(base[s2 >> 16] + (s2 & 0xFFFF)) * DMODEL);
    const float4* y3 = (const float4*)(ys + (size_t)(base[s3 >> 16] + (s3 & 0xFFFF)) * DMODEL);
    int i = threadIdx.x;
    float4 a = y0[i], b = y1[i], c = y2[i], d = y3[i];
    float4 o;
    o.x = a.x + b.x + c.x + d.x;
    o.y = a.y + b.y + c.y + d.y;
    o.z = a.z + b.z + c.z + d.z;
    o.w = a.w + b.w + c.w + d.w;
    ((float4*)(out + (size_t)tok * DMODEL))[i] = o;
}

// ---------------- fp32 fallback (only if workspace too small) ----------------
#define BTF 16
__global__ __launch_bounds__(256) void expert_k(
    const float* __restrict__ x, const float* __restrict__ keys,
    const float* __restrict__ values, const int* __restrict__ counts,
    const int* __restrict__ tok_list, const float* __restrict__ gate_list,
    float* __restrict__ out, int ntok)
{
    int e   = blockIdx.y;
    int cnt = counts[e];
    int t0  = blockIdx.x * BTF;
    if (t0 >= cnt) return;
    int nt = (cnt - t0 < BTF) ? (cnt - t0) : BTF;

    __shared__ float xs[BTF][DMODEL];
    __shared__ float hsl[BTF][FDIM];
    __shared__ int   toks[BTF];
    __shared__ float gts[BTF];

    if (threadIdx.x < BTF) {
        int t = threadIdx.x;
        bool live = (t < nt);
        toks[t] = live ? tok_list [(size_t)e * ntok + t0 + t] : 0;
        gts[t]  = live ? gate_list[(size_t)e * ntok + t0 + t] : 0.f;
    }
    __syncthreads();
    for (int i = threadIdx.x; i < BTF * (DMODEL / 4); i += 256) {
        int r = i >> 8, c = i & 255;
        ((float4*)xs[r])[c] = ((const float4*)(x + (size_t)toks[r] * DMODEL))[c];
    }
    __syncthreads();

    {
        int f = threadIdx.x * 2;
        float acc0[BTF], acc1[BTF];
        #pragma unroll
        for (int t = 0; t < BTF; t++) { acc0[t] = 0.f; acc1[t] = 0.f; }
        const float* kp = keys + (size_t)e * DMODEL * FDIM + f;
        for (int k = 0; k < DMODEL; k += 4) {
            const float* kr = kp + (size_t)k * FDIM;
            float2 kv0 = *(const float2*)(kr);
            float2 kv1 = *(const float2*)(kr + FDIM);
            float2 kv2 = *(const float2*)(kr + 2 * FDIM);
            float2 kv3 = *(const float2*)(kr + 3 * FDIM);
            #pragma unroll
            for (int t = 0; t < BTF; t++) {
                float4 xv = *(const float4*)(&xs[t][k]);
                acc0[t] += xv.x * kv0.x + xv.y * kv1.x + xv.z * kv2.x + xv.w * kv3.x;
                acc1[t] += xv.x * kv0.y + xv.y * kv1.y + xv.z * kv2.y + xv.w * kv3.y;
            }
        }
        #pragma unroll
        for (int t = 0; t < BTF; t++) {
            float g = gts[t];
            hsl[t][f]     = fmaxf(acc0[t], 0.f) * g;
            hsl[t][f + 1] = fmaxf(acc1[t], 0.f) * g;
        }
    }
    __syncthreads();

    {
        int v = threadIdx.x * 4;
        float acc[BTF][4];
        #pragma unroll
        for (int t = 0; t < BTF; t++) { acc[t][0]=0.f; acc[t][1]=0.f; acc[t][2]=0.f; acc[t][3]=0.f; }
        const float* vp = values + (size_t)e * FDIM * DMODEL + v;
        for (int k = 0; k < FDIM; k += 2) {
            float4 va0 = *(const float4*)(vp + (size_t)k * DMODEL);
            float4 va1 = *(const float4*)(vp + (size_t)(k + 1) * DMODEL);
            #pragma unroll
            for (int t = 0; t < BTF; t++) {
                float2 hv = *(const float2*)(&hsl[t][k]);
                acc[t][0] += hv.x * va0.x + hv.y * va1.x;
                acc[t][1] += hv.x * va0.y + hv.y * va1.y;
                acc[t][2] += hv.x * va0.z + hv.y * va1.z;
                acc[t][3] += hv.x * va0.w + hv.y * va1.w;
            }
        }
        #pragma unroll
        for (int t = 0; t < BTF; t++) {
            if (t < nt) {
                float* orow = out + (size_t)toks[t] * DMODEL + v;
                atomicAdd(orow + 0, acc[t][0]);
                atomicAdd(orow + 1, acc[t][1]);
                atomicAdd(orow + 2, acc[t][2]);
                atomicAdd(orow + 3, acc[t][3]);
            }
        }
    }
}

extern "C" void kernel_launch(void* const* d_in, const int* in_sizes, int n_in,
                              void* d_out, int out_size, void* d_ws, size_t ws_size,
                              hipStream_t stream) {
    const float* x      = (const float*)d_in[0];
    const float* esel   = (const float*)d_in[1];
    const float* keys   = (const float*)d_in[2];
    const float* values = (const float*)d_in[3];
    float* out = (float*)d_out;
    int ntok = in_sizes[0] / DMODEL;

    // workspace layout
    const size_t OFF_BASE = 512;
    const size_t OFF_NT   = 1024;
    const size_t OFF_TILE = 2048;
    const size_t OFF_HIST = 16 << 10;
    const size_t OFF_GOFF = 32 << 10;
    const size_t OFF_SLOT = 64 << 10;
    const size_t OFF_SELE = 128 << 10;
    const size_t OFF_SELG = 192 << 10;
    const size_t OFF_TOK  = 256 << 10;
    const size_t OFF_GATE = 1ull << 20;
    const size_t OFF_XB   = 2ull << 20;
    const size_t OFF_KT   = 12ull << 20;
    const size_t OFF_VT   = 46ull << 20;
    const size_t OFF_HS   = 80ull << 20;
    const size_t OFF_YS   = 98ull << 20;
    const size_t NEED     = OFF_YS + (size_t)ntok * TOPK * DMODEL * sizeof(float) + (1 << 20);

    int*      counts    = (int*)d_ws;
    int*      ebase     = (int*)((char*)d_ws + OFF_BASE);
    int*      ntiles    = (int*)((char*)d_ws + OFF_NT);
    int*      tiles     = (int*)((char*)d_ws + OFF_TILE);
    int*      ghist     = (int*)((char*)d_ws + OFF_HIST);
    int*      goff      = (int*)((char*)d_ws + OFF_GOFF);
    unsigned* slotinfo  = (unsigned*)((char*)d_ws + OFF_SLOT);
    unsigned* sel_e     = (unsigned*)((char*)d_ws + OFF_SELE);
    float*    sel_g     = (float*)((char*)d_ws + OFF_SELG);
    int*      tok_list  = (int*)((char*)d_ws + OFF_TOK);
    float*    gate_list = (float*)((char*)d_ws + OFF_GATE);
    unsigned short* xb  = (unsigned short*)((char*)d_ws + OFF_XB);

    int nsel = ntok * TOPK;
    int rblocks = (ntok + RTB - 1) / RTB;
    route_a<<<rblocks, 256, 0, stream>>>(x, esel, xb, sel_e, sel_g, ntok);
    hist_k<<<NBORD, 256, 0, stream>>>(sel_e, ghist, nsel);
    scan2_k<<<1, 64, 0, stream>>>(ghist, goff, counts, ebase, tiles, ntiles, NBORD);
    scat_k<<<NBORD, 256, 0, stream>>>(sel_e, sel_g, goff, tok_list, gate_list,
                                      slotinfo, nsel, ntok);

    if (ws_size >= NEED) {
        unsigned short* kt = (unsigned short*)((char*)d_ws + OFF_KT);
        unsigned short* vt = (unsigned short*)((char*)d_ws + OFF_VT);
        unsigned short* hs = (unsigned short*)((char*)d_ws + OFF_HS);
        float*          ys = (float*)((char*)d_ws + OFF_YS);

        prep_t<<<dim3(FDIM / 64, DMODEL / 64, NEXP), 256, 0, stream>>>(keys,   kt, DMODEL, FDIM);
        prep_t<<<dim3(DMODEL / 64, FDIM / 64, NEXP), 256, 0, stream>>>(values, vt, FDIM, DMODEL);

        int maxt = (ntok * TOPK + MT - 1) / MT + NEXP;
        gemm1_k<<<dim3(maxt, FDIM / NT), 256, 0, stream>>>(
            xb, kt, counts, ebase, tiles, ntiles, tok_list, gate_list, hs, ntok);
        gemm2_k<<<dim3(maxt, DMODEL / NT), 256, 0, stream>>>(
            hs, vt, counts, ebase, tiles, ntiles, ys);
        combine_k<<<ntok, 256, 0, stream>>>(ys, slotinfo, ebase, out);
    } else {
        hipMemsetAsync(out, 0, (size_t)out_size * sizeof(float), stream);
        int ntiles2 = (ntok + BTF - 1) / BTF;
        expert_k<<<dim3(ntiles2, NEXP), 256, 0, stream>>>(
            x, keys, values, counts, tok_list, gate_list, out, ntok);
    }
}

// Round 15
// 196.504 us; speedup vs baseline: 1.0755x; 1.0290x over previous
//
#include <hip/hip_runtime.h>

#define DMODEL 1024
#define NEXP   32
#define FDIM   512
#define TOPK   4

#define MT    128   // token tile
#define NT    128   // f / v tile
#define BK    64    // k per stage (2 MFMA k-slices)
#define RTB   8     // tokens per routing block
#define NBORD 64    // blocks for hist/scatter phases

using short8 = __attribute__((ext_vector_type(8))) short;
using f32x4  = __attribute__((ext_vector_type(4))) float;

#define AS1 __attribute__((address_space(1)))
#define AS3 __attribute__((address_space(3)))
__device__ __forceinline__ void gload_lds16(const void* g, void* l) {
    // async global->LDS DMA, 16B/lane; LDS dest = (uniform base) + lane*16
    __builtin_amdgcn_global_load_lds((const AS1 unsigned int*)g, (AS3 unsigned int*)l, 16, 0, 0);
}

__device__ __forceinline__ unsigned short f2b(float f) {
    unsigned int u = __float_as_uint(f);
    unsigned int r = (u + 0x7FFFu + ((u >> 16) & 1u)) >> 16;   // RNE bf16
    return (unsigned short)r;
}
__device__ __forceinline__ float b2f(unsigned short u) {
    return __uint_as_float((unsigned int)u << 16);
}

// ------- phase A: gates + top-4 -> sel arrays (NO atomics) + x->bf16 -------
__global__ __launch_bounds__(256) void route_a(
    const float* __restrict__ x, const float* __restrict__ esel,
    unsigned short* __restrict__ xb,
    unsigned int* __restrict__ sel_e, float* __restrict__ sel_g, int ntok)
{
    int tile0 = blockIdx.x * RTB;
    int tid = threadIdx.x;

    __shared__ float xs[RTB][DMODEL];   // 32 KB
    __shared__ float gs[RTB][NEXP];     // 1 KB

    {
        const float4* src = (const float4*)(x + (size_t)tile0 * DMODEL);
        float4* dst = (float4*)&xs[0][0];
        int navail = min(RTB, ntok - tile0) * (DMODEL / 4);
        for (int i = tid; i < RTB * (DMODEL / 4); i += 256)
            dst[i] = src[i < navail ? i : 0];
    }
    __syncthreads();

    int e = tid >> 3, sub = tid & 7;
    float4 acc0 = {0,0,0,0}, acc1 = {0,0,0,0}, acc2 = {0,0,0,0}, acc3 = {0,0,0,0};
    float4 acc4 = {0,0,0,0}, acc5 = {0,0,0,0}, acc6 = {0,0,0,0}, acc7 = {0,0,0,0};
    const float* er = esel + (size_t)e * DMODEL + sub * 4;
    #pragma unroll 4
    for (int j = 0; j < DMODEL / 32; j++) {
        float4 ev = *(const float4*)(er + j * 32);
        int kk = sub * 4 + j * 32;
        float4 x0 = *(const float4*)(&xs[0][kk]);
        float4 x1 = *(const float4*)(&xs[1][kk]);
        float4 x2 = *(const float4*)(&xs[2][kk]);
        float4 x3 = *(const float4*)(&xs[3][kk]);
        float4 x4 = *(const float4*)(&xs[4][kk]);
        float4 x5 = *(const float4*)(&xs[5][kk]);
        float4 x6 = *(const float4*)(&xs[6][kk]);
        float4 x7 = *(const float4*)(&xs[7][kk]);
        acc0.x += ev.x*x0.x; acc0.y += ev.y*x0.y; acc0.z += ev.z*x0.z; acc0.w += ev.w*x0.w;
        acc1.x += ev.x*x1.x; acc1.y += ev.y*x1.y; acc1.z += ev.z*x1.z; acc1.w += ev.w*x1.w;
        acc2.x += ev.x*x2.x; acc2.y += ev.y*x2.y; acc2.z += ev.z*x2.z; acc2.w += ev.w*x2.w;
        acc3.x += ev.x*x3.x; acc3.y += ev.y*x3.y; acc3.z += ev.z*x3.z; acc3.w += ev.w*x3.w;
        acc4.x += ev.x*x4.x; acc4.y += ev.y*x4.y; acc4.z += ev.z*x4.z; acc4.w += ev.w*x4.w;
        acc5.x += ev.x*x5.x; acc5.y += ev.y*x5.y; acc5.z += ev.z*x5.z; acc5.w += ev.w*x5.w;
        acc6.x += ev.x*x6.x; acc6.y += ev.y*x6.y; acc6.z += ev.z*x6.z; acc6.w += ev.w*x6.w;
        acc7.x += ev.x*x7.x; acc7.y += ev.y*x7.y; acc7.z += ev.z*x7.z; acc7.w += ev.w*x7.w;
    }
    {
        float s[RTB] = {
            acc0.x+acc0.y+acc0.z+acc0.w, acc1.x+acc1.y+acc1.z+acc1.w,
            acc2.x+acc2.y+acc2.z+acc2.w, acc3.x+acc3.y+acc3.z+acc3.w,
            acc4.x+acc4.y+acc4.z+acc4.w, acc5.x+acc5.y+acc5.z+acc5.w,
            acc6.x+acc6.y+acc6.z+acc6.w, acc7.x+acc7.y+acc7.z+acc7.w };
        #pragma unroll
        for (int t = 0; t < RTB; t++) {
            float v = s[t];
            v += __shfl_xor(v, 1);
            v += __shfl_xor(v, 2);
            v += __shfl_xor(v, 4);
            if (sub == 0) gs[t][e] = 1.f / (1.f + expf(-v));
        }
    }
    __syncthreads();

    {
        int t = tid >> 5, e2 = tid & 31;
        int tok = tile0 + t;
        if (tok < ntok) {
            float v = gs[t][e2];
            #pragma unroll
            for (int r = 0; r < TOPK; r++) {
                float bv = v; int bi = e2;
                #pragma unroll
                for (int sft = 16; sft >= 1; sft >>= 1) {
                    float ov = __shfl_xor(bv, sft, 32);
                    int   oi = __shfl_xor(bi, sft, 32);
                    if (ov > bv || (ov == bv && oi < bi)) { bv = ov; bi = oi; }
                }
                if (e2 == bi) v = -1e30f;
                if (e2 == r) {
                    sel_e[(size_t)tok * TOPK + r] = (unsigned)bi;
                    sel_g[(size_t)tok * TOPK + r] = bv;
                }
            }
        }
    }

    {
        int navail = min(RTB, ntok - tile0) * (DMODEL / 4);
        ushort4* dst = (ushort4*)(xb + (size_t)tile0 * DMODEL);
        const float4* srcl = (const float4*)&xs[0][0];
        for (int i = tid; i < navail; i += 256) {
            float4 v = srcl[i];
            ushort4 o;
            o.x = f2b(v.x); o.y = f2b(v.y); o.z = f2b(v.z); o.w = f2b(v.w);
            dst[i] = o;
        }
    }
}

// ------- phase B1: per-block expert histogram -------
__global__ __launch_bounds__(256) void hist_k(
    const unsigned int* __restrict__ sel_e, int* __restrict__ ghist, int nsel)
{
    __shared__ int h[NEXP];
    int tid = threadIdx.x;
    if (tid < NEXP) h[tid] = 0;
    __syncthreads();
    int chunk = (nsel + gridDim.x - 1) / gridDim.x;
    int i0 = blockIdx.x * chunk, i1 = min(i0 + chunk, nsel);
    for (int i = i0 + tid; i < i1; i += 256)
        atomicAdd(&h[sel_e[i]], 1);
    __syncthreads();
    if (tid < NEXP) ghist[blockIdx.x * NEXP + tid] = h[tid];
}

// ------- phase B2: prefix over blocks per expert + base + tile list -------
__global__ __launch_bounds__(64) void scan2_k(
    const int* __restrict__ ghist, int* __restrict__ goff,
    int* __restrict__ counts, int* __restrict__ base,
    int* __restrict__ tiles, int* __restrict__ ntiles, int nb)
{
    int e = threadIdx.x;
    if (e < NEXP) {
        int s = 0;
        for (int b = 0; b < nb; b++) {
            goff[b * NEXP + e] = s;
            s += ghist[b * NEXP + e];
        }
        counts[e] = s;
    }
    __syncthreads();
    if (e == 0) {
        int s = 0, nt = 0;
        for (int e2 = 0; e2 < NEXP; e2++) {
            base[e2] = s;
            int c = counts[e2];
            for (int t0 = 0; t0 < c; t0 += MT) tiles[nt++] = (e2 << 8) | (t0 / MT);
            s += c;
        }
        *ntiles = nt;
    }
}

// ------- phase B3: scatter into lists (LDS counters seeded by goff) -------
__global__ __launch_bounds__(256) void scat_k(
    const unsigned int* __restrict__ sel_e, const float* __restrict__ sel_g,
    const int* __restrict__ goff,
    int* __restrict__ tok_list, float* __restrict__ gate_list,
    unsigned int* __restrict__ slotinfo, int nsel, int ntok)
{
    __shared__ int c[NEXP];
    int tid = threadIdx.x;
    if (tid < NEXP) c[tid] = goff[blockIdx.x * NEXP + tid];
    __syncthreads();
    int chunk = (nsel + gridDim.x - 1) / gridDim.x;
    int i0 = blockIdx.x * chunk, i1 = min(i0 + chunk, nsel);
    for (int i = i0 + tid; i < i1; i += 256) {
        unsigned int e = sel_e[i];
        float g = sel_g[i];
        int pos = atomicAdd(&c[e], 1);
        tok_list [(size_t)e * ntok + pos] = i >> 2;
        gate_list[(size_t)e * ntok + pos] = g;
        slotinfo[i] = (e << 16) | (unsigned)pos;
    }
}

// ------- prep: transpose+convert  src[e][R][C] f32  ->  dst[e][C][R] bf16 -------
__global__ __launch_bounds__(256) void prep_t(const float* __restrict__ src,
                                              unsigned short* __restrict__ dst,
                                              int R, int C) {
    __shared__ float tile[64][65];
    int e  = blockIdx.z;
    int r0 = blockIdx.y * 64, c0 = blockIdx.x * 64;
    const float* s = src + (size_t)e * R * C;
    unsigned short* d = dst + (size_t)e * R * C;
    for (int i = 0; i < 16; i++) {
        int c = i * 256 + threadIdx.x;
        int rr = c >> 6, cc = c & 63;
        tile[rr][cc] = s[(size_t)(r0 + rr) * C + c0 + cc];
    }
    __syncthreads();
    for (int i = 0; i < 16; i++) {
        int c = i * 256 + threadIdx.x;
        int wr = c >> 6, wc = c & 63;
        d[(size_t)(c0 + wr) * R + r0 + wc] = f2b(tile[wc][wr]);
    }
}

// ---- GEMM1: hs = relu(x . K_e)*gate  (BK=64, gload_lds + XOR-swizzled reads) ----
// LDS tiles [128 rows][64 k] bf16 = 128B rows. Source pre-swizzle: lane chunk
// (l&7)^(l>>3); read swizzle: chunk' = (ks*4+lg)^(row&7). 2-way banks = free.
__global__ __launch_bounds__(256) void gemm1_k(
    const unsigned short* __restrict__ xb,
    const unsigned short* __restrict__ kt,   // [E][512 f][1024 d]
    const int* __restrict__ counts, const int* __restrict__ base,
    const int* __restrict__ tiles, const int* __restrict__ ntiles,
    const int* __restrict__ tok_list, const float* __restrict__ gate_list,
    unsigned short* __restrict__ hs, int ntok)
{
    int ti = blockIdx.x;
    if (ti >= *ntiles) return;
    int code = tiles[ti];
    int e = code >> 8, t0 = (code & 255) * MT;
    int cnt  = counts[e];
    int f0   = blockIdx.y * NT;
    int live = min(MT, cnt - t0);

    __shared__ unsigned short Xs[MT * BK];   // 16 KB
    __shared__ unsigned short Ks[NT * BK];   // 16 KB
    __shared__ int   toks[MT];
    __shared__ float gts[MT];

    int tid = threadIdx.x, lane = tid & 63, w = tid >> 6;
    int lr = lane & 15, lg = lane >> 4;

    if (tid < MT) {
        bool lv = tid < live;
        toks[tid] = lv ? tok_list [(size_t)e * ntok + t0 + tid] : 0;
        gts[tid]  = lv ? gate_list[(size_t)e * ntok + t0 + tid] : 0.f;
    }
    __syncthreads();

    // staging: 16 chunks/operand (1 KB = 8 rows x 128 B); wave w owns chunks 4w..4w+3
    int lrow = lane >> 3;                        // row within chunk 0..7 (== row&7)
    int scol = ((lane & 7) ^ lrow) * 8;          // pre-swizzled ushort col
    const unsigned short* ke = kt + (size_t)e * FDIM * DMODEL + (size_t)f0 * DMODEL;
    const unsigned short* sx[4];
    const unsigned short* sk[4];
    unsigned short* dx[4];
    unsigned short* dk[4];
    #pragma unroll
    for (int j = 0; j < 4; j++) {
        int ch = 4 * w + j;
        int row = ch * 8 + lrow;
        sx[j] = xb + (size_t)toks[row] * DMODEL + scol;
        sk[j] = ke + (size_t)row * DMODEL + scol;
        dx[j] = Xs + ch * 512;
        dk[j] = Ks + ch * 512;
    }

    f32x4 acc[8][2];
    #pragma unroll
    for (int m = 0; m < 8; m++)
        #pragma unroll
        for (int n = 0; n < 2; n++)
            acc[m][n] = (f32x4){0.f, 0.f, 0.f, 0.f};

    for (int k0 = 0; k0 < DMODEL; k0 += BK) {
        #pragma unroll
        for (int j = 0; j < 4; j++) {
            gload_lds16(sx[j] + k0, dx[j]);
            gload_lds16(sk[j] + k0, dk[j]);
        }
        __syncthreads();                     // drains vmcnt -> tiles ready
        #pragma unroll
        for (int ks = 0; ks < 2; ks++) {
            short8 a[8];
            #pragma unroll
            for (int m = 0; m < 8; m++) {
                int row = m * 16 + lr;
                a[m] = *(const short8*)(Xs + row * BK + (((ks * 4 + lg) ^ (lr & 7)) * 8));
            }
            #pragma unroll
            for (int n = 0; n < 2; n++) {
                int row = w * 32 + n * 16 + lr;
                short8 b = *(const short8*)(Ks + row * BK + (((ks * 4 + lg) ^ (lr & 7)) * 8));
                #pragma unroll
                for (int m = 0; m < 8; m++)
                    acc[m][n] = __builtin_amdgcn_mfma_f32_16x16x32_bf16(a[m], b, acc[m][n], 0, 0, 0);
            }
        }
        __syncthreads();
    }

    int hb = base[e] + t0;
    #pragma unroll
    for (int m = 0; m < 8; m++) {
        #pragma unroll
        for (int n = 0; n < 2; n++) {
            int col = f0 + w * 32 + n * 16 + lr;
            #pragma unroll
            for (int r = 0; r < 4; r++) {
                int row = m * 16 + lg * 4 + r;
                if (row < live)
                    hs[(size_t)(hb + row) * FDIM + col] = f2b(fmaxf(acc[m][n][r], 0.f) * gts[row]);
            }
        }
    }
}

// ---- GEMM2: ys(bf16) = hs . V_e  (BK=64, gload_lds + XOR-swizzled reads) ----
__global__ __launch_bounds__(256) void gemm2_k(
    const unsigned short* __restrict__ hs,
    const unsigned short* __restrict__ vt,   // [E][1024 v][512 f]
    const int* __restrict__ counts, const int* __restrict__ base,
    const int* __restrict__ tiles, const int* __restrict__ ntiles,
    unsigned short* __restrict__ ys)
{
    int ti = blockIdx.x;
    if (ti >= *ntiles) return;
    int code = tiles[ti];
    int e = code >> 8, t0 = (code & 255) * MT;
    int cnt  = counts[e];
    int v0   = blockIdx.y * NT;
    int live = min(MT, cnt - t0);
    int hb   = base[e] + t0;

    __shared__ unsigned short Hs[MT * BK];   // 16 KB
    __shared__ unsigned short Vs[NT * BK];   // 16 KB

    int tid = threadIdx.x, lane = tid & 63, w = tid >> 6;
    int lr = lane & 15, lg = lane >> 4;

    int lrow = lane >> 3;
    int scol = ((lane & 7) ^ lrow) * 8;
    const unsigned short* he = hs + (size_t)hb * FDIM;
    const unsigned short* ve = vt + (size_t)e * DMODEL * FDIM + (size_t)v0 * FDIM;
    const unsigned short* sh[4];
    const unsigned short* sv[4];
    unsigned short* dh[4];
    unsigned short* dv[4];
    #pragma unroll
    for (int j = 0; j < 4; j++) {
        int ch = 4 * w + j;
        int row = ch * 8 + lrow;
        sh[j] = he + (size_t)row * FDIM + scol;      // may over-read slack rows
        sv[j] = ve + (size_t)row * FDIM + scol;
        dh[j] = Hs + ch * 512;
        dv[j] = Vs + ch * 512;
    }

    f32x4 acc[8][2];
    #pragma unroll
    for (int m = 0; m < 8; m++)
        #pragma unroll
        for (int n = 0; n < 2; n++)
            acc[m][n] = (f32x4){0.f, 0.f, 0.f, 0.f};

    for (int k0 = 0; k0 < FDIM; k0 += BK) {
        #pragma unroll
        for (int j = 0; j < 4; j++) {
            gload_lds16(sh[j] + k0, dh[j]);
            gload_lds16(sv[j] + k0, dv[j]);
        }
        __syncthreads();
        #pragma unroll
        for (int ks = 0; ks < 2; ks++) {
            short8 a[8];
            #pragma unroll
            for (int m = 0; m < 8; m++) {
                int row = m * 16 + lr;
                a[m] = *(const short8*)(Hs + row * BK + (((ks * 4 + lg) ^ (lr & 7)) * 8));
            }
            #pragma unroll
            for (int n = 0; n < 2; n++) {
                int row = w * 32 + n * 16 + lr;
                short8 b = *(const short8*)(Vs + row * BK + (((ks * 4 + lg) ^ (lr & 7)) * 8));
                #pragma unroll
                for (int m = 0; m < 8; m++)
                    acc[m][n] = __builtin_amdgcn_mfma_f32_16x16x32_bf16(a[m], b, acc[m][n], 0, 0, 0);
            }
        }
        __syncthreads();
    }

    #pragma unroll
    for (int m = 0; m < 8; m++) {
        #pragma unroll
        for (int n = 0; n < 2; n++) {
            int col = v0 + w * 32 + n * 16 + lr;
            #pragma unroll
            for (int r = 0; r < 4; r++) {
                int row = m * 16 + lg * 4 + r;
                if (row < live)
                    ys[(size_t)(hb + row) * DMODEL + col] = f2b(acc[m][n][r]);
            }
        }
    }
}

// ------- combine: out[tok] = sum of the token's 4 slot rows (bf16 ys) -------
__global__ __launch_bounds__(256) void combine_k(
    const unsigned short* __restrict__ ys, const unsigned int* __restrict__ slotinfo,
    const int* __restrict__ base, float* __restrict__ out)
{
    int tok = blockIdx.x;
    unsigned int s0 = slotinfo[(size_t)tok * TOPK + 0];
    unsigned int s1 = slotinfo[(size_t)tok * TOPK + 1];
    unsigned int s2 = slotinfo[(size_t)tok * TOPK + 2];
    unsigned int s3 = slotinfo[(size_t)tok * TOPK + 3];
    const ushort4* y0 = (const ushort4*)(ys + (size_t)(base[s0 >> 16] + (s0 & 0xFFFF)) * DMODEL);
    const ushort4* y1 = (const ushort4*)(ys + (size_t)(base[s1 >> 16] + (s1 & 0xFFFF)) * DMODEL);
    const ushort4* y2 = (const ushort4*)(ys + (size_t)(base[s2 >> 16] + (s2 & 0xFFFF)) * DMODEL);
    const ushort4* y3 = (const ushort4*)(ys + (size_t)(base[s3 >> 16] + (s3 & 0xFFFF)) * DMODEL);
    int i = threadIdx.x;
    ushort4 a = y0[i], b = y1[i], c = y2[i], d = y3[i];
    float4 o;
    o.x = b2f(a.x) + b2f(b.x) + b2f(c.x) + b2f(d.x);
    o.y = b2f(a.y) + b2f(b.y) + b2f(c.y) + b2f(d.y);
    o.z = b2f(a.z) + b2f(b.z) + b2f(c.z) + b2f(d.z);
    o.w = b2f(a.w) + b2f(b.w) + b2f(c.w) + b2f(d.w);
    ((float4*)(out + (size_t)tok * DMODEL))[i] = o;
}

// ---------------- fp32 fallback (only if workspace too small) ----------------
#define BTF 16
__global__ __launch_bounds__(256) void expert_k(
    const float* __restrict__ x, const float* __restrict__ keys,
    const float* __restrict__ values, const int* __restrict__ counts,
    const int* __restrict__ tok_list, const float* __restrict__ gate_list,
    float* __restrict__ out, int ntok)
{
    int e   = blockIdx.y;
    int cnt = counts[e];
    int t0  = blockIdx.x * BTF;
    if (t0 >= cnt) return;
    int nt = (cnt - t0 < BTF) ? (cnt - t0) : BTF;

    __shared__ float xs[BTF][DMODEL];
    __shared__ float hsl[BTF][FDIM];
    __shared__ int   toks[BTF];
    __shared__ float gts[BTF];

    if (threadIdx.x < BTF) {
        int t = threadIdx.x;
        bool live = (t < nt);
        toks[t] = live ? tok_list [(size_t)e * ntok + t0 + t] : 0;
        gts[t]  = live ? gate_list[(size_t)e * ntok + t0 + t] : 0.f;
    }
    __syncthreads();
    for (int i = threadIdx.x; i < BTF * (DMODEL / 4); i += 256) {
        int r = i >> 8, c = i & 255;
        ((float4*)xs[r])[c] = ((const float4*)(x + (size_t)toks[r] * DMODEL))[c];
    }
    __syncthreads();

    {
        int f = threadIdx.x * 2;
        float acc0[BTF], acc1[BTF];
        #pragma unroll
        for (int t = 0; t < BTF; t++) { acc0[t] = 0.f; acc1[t] = 0.f; }
        const float* kp = keys + (size_t)e * DMODEL * FDIM + f;
        for (int k = 0; k < DMODEL; k += 4) {
            const float* kr = kp + (size_t)k * FDIM;
            float2 kv0 = *(const float2*)(kr);
            float2 kv1 = *(const float2*)(kr + FDIM);
            float2 kv2 = *(const float2*)(kr + 2 * FDIM);
            float2 kv3 = *(const float2*)(kr + 3 * FDIM);
            #pragma unroll
            for (int t = 0; t < BTF; t++) {
                float4 xv = *(const float4*)(&xs[t][k]);
                acc0[t] += xv.x * kv0.x + xv.y * kv1.x + xv.z * kv2.x + xv.w * kv3.x;
                acc1[t] += xv.x * kv0.y + xv.y * kv1.y + xv.z * kv2.y + xv.w * kv3.y;
            }
        }
        #pragma unroll
        for (int t = 0; t < BTF; t++) {
            float g = gts[t];
            hsl[t][f]     = fmaxf(acc0[t], 0.f) * g;
            hsl[t][f + 1] = fmaxf(acc1[t], 0.f) * g;
        }
    }
    __syncthreads();

    {
        int v = threadIdx.x * 4;
        float acc[BTF][4];
        #pragma unroll
        for (int t = 0; t < BTF; t++) { acc[t][0]=0.f; acc[t][1]=0.f; acc[t][2]=0.f; acc[t][3]=0.f; }
        const float* vp = values + (size_t)e * FDIM * DMODEL + v;
        for (int k = 0; k < FDIM; k += 2) {
            float4 va0 = *(const float4*)(vp + (size_t)k * DMODEL);
            float4 va1 = *(const float4*)(vp + (size_t)(k + 1) * DMODEL);
            #pragma unroll
            for (int t = 0; t < BTF; t++) {
                float2 hv = *(const float2*)(&hsl[t][k]);
                acc[t][0] += hv.x * va0.x + hv.y * va1.x;
                acc[t][1] += hv.x * va0.y + hv.y * va1.y;
                acc[t][2] += hv.x * va0.z + hv.y * va1.z;
                acc[t][3] += hv.x * va0.w + hv.y * va1.w;
            }
        }
        #pragma unroll
        for (int t = 0; t < BTF; t++) {
            if (t < nt) {
                float* orow = out + (size_t)toks[t] * DMODEL + v;
                atomicAdd(orow + 0, acc[t][0]);
                atomicAdd(orow + 1, acc[t][1]);
                atomicAdd(orow + 2, acc[t][2]);
                atomicAdd(orow + 3, acc[t][3]);
            }
        }
    }
}

extern "C" void kernel_launch(void* const* d_in, const int* in_sizes, int n_in,
                              void* d_out, int out_size, void* d_ws, size_t ws_size,
                              hipStream_t stream) {
    const float* x      = (const float*)d_in[0];
    const float* esel   = (const float*)d_in[1];
    const float* keys   = (const float*)d_in[2];
    const float* values = (const float*)d_in[3];
    float* out = (float*)d_out;
    int ntok = in_sizes[0] / DMODEL;

    // workspace layout
    const size_t OFF_BASE = 512;
    const size_t OFF_NT   = 1024;
    const size_t OFF_TILE = 2048;
    const size_t OFF_HIST = 16 << 10;
    const size_t OFF_GOFF = 32 << 10;
    const size_t OFF_SLOT = 64 << 10;
    const size_t OFF_SELE = 128 << 10;
    const size_t OFF_SELG = 192 << 10;
    const size_t OFF_TOK  = 256 << 10;
    const size_t OFF_GATE = 1ull << 20;
    const size_t OFF_XB   = 2ull << 20;
    const size_t OFF_KT   = 12ull << 20;
    const size_t OFF_VT   = 46ull << 20;
    const size_t OFF_HS   = 80ull << 20;
    const size_t OFF_YS   = 98ull << 20;
    const size_t NEED     = OFF_YS + (size_t)ntok * TOPK * DMODEL * sizeof(float) + (1 << 20);

    int*      counts    = (int*)d_ws;
    int*      ebase     = (int*)((char*)d_ws + OFF_BASE);
    int*      ntiles    = (int*)((char*)d_ws + OFF_NT);
    int*      tiles     = (int*)((char*)d_ws + OFF_TILE);
    int*      ghist     = (int*)((char*)d_ws + OFF_HIST);
    int*      goff      = (int*)((char*)d_ws + OFF_GOFF);
    unsigned* slotinfo  = (unsigned*)((char*)d_ws + OFF_SLOT);
    unsigned* sel_e     = (unsigned*)((char*)d_ws + OFF_SELE);
    float*    sel_g     = (float*)((char*)d_ws + OFF_SELG);
    int*      tok_list  = (int*)((char*)d_ws + OFF_TOK);
    float*    gate_list = (float*)((char*)d_ws + OFF_GATE);
    unsigned short* xb  = (unsigned short*)((char*)d_ws + OFF_XB);

    int nsel = ntok * TOPK;
    int rblocks = (ntok + RTB - 1) / RTB;
    route_a<<<rblocks, 256, 0, stream>>>(x, esel, xb, sel_e, sel_g, ntok);
    hist_k<<<NBORD, 256, 0, stream>>>(sel_e, ghist, nsel);
    scan2_k<<<1, 64, 0, stream>>>(ghist, goff, counts, ebase, tiles, ntiles, NBORD);
    scat_k<<<NBORD, 256, 0, stream>>>(sel_e, sel_g, goff, tok_list, gate_list,
                                      slotinfo, nsel, ntok);

    if (ws_size >= NEED) {
        unsigned short* kt = (unsigned short*)((char*)d_ws + OFF_KT);
        unsigned short* vt = (unsigned short*)((char*)d_ws + OFF_VT);
        unsigned short* hs = (unsigned short*)((char*)d_ws + OFF_HS);
        unsigned short* ys = (unsigned short*)((char*)d_ws + OFF_YS);

        prep_t<<<dim3(FDIM / 64, DMODEL / 64, NEXP), 256, 0, stream>>>(keys,   kt, DMODEL, FDIM);
        prep_t<<<dim3(DMODEL / 64, FDIM / 64, NEXP), 256, 0, stream>>>(values, vt, FDIM, DMODEL);

        int maxt = (ntok * TOPK + MT - 1) / MT + NEXP;
        gemm1_k<<<dim3(maxt, FDIM / NT), 256, 0, stream>>>(
            xb, kt, counts, ebase, tiles, ntiles, tok_list, gate_list, hs, ntok);
        gemm2_k<<<dim3(maxt, DMODEL / NT), 256, 0, stream>>>(
            hs, vt, counts, ebase, tiles, ntiles, ys);
        combine_k<<<ntok, 256, 0, stream>>>(ys, slotinfo, ebase, out);
    } else {
        hipMemsetAsync(out, 0, (size_t)out_size * sizeof(float), stream);
        int ntiles2 = (ntok + BTF - 1) / BTF;
        expert_k<<<dim3(ntiles2, NEXP), 256, 0, stream>>>(
            x, keys, values, counts, tok_list, gate_list, out, ntok);
    }
}